// Round 2
// baseline (2101.695 us; speedup 1.0000x reference)
//
#include <hip/hip_runtime.h>
#include <hip/hip_bf16.h>

#define N_NODES 40000
#define N_EDGES 640000
#define DIM_IN 64
#define DIM_H 128
#define DIM_OUT 32
#define DIM_ED 16
#define HEADS 2
#define NEG_SLOPE 0.2f

// ---------------------------------------------------------------------------
// CSR build: degree + edge-attr mean (for self-loop fill), scan, scatter
// ---------------------------------------------------------------------------
__global__ void deg_ea_kernel(const int* __restrict__ tgt, const float* __restrict__ edge_attr,
                              int* __restrict__ deg, float* __restrict__ ea_sum, int E_) {
    int e = blockIdx.x * 256 + threadIdx.x;
    if (e >= E_) return;
    int t = tgt[e];
    atomicAdd(&deg[t], 1);
    const float* ea = edge_attr + (size_t)e * DIM_ED;
    float* dst = ea_sum + (size_t)t * DIM_ED;
    #pragma unroll
    for (int d = 0; d < DIM_ED; d++) atomicAdd(&dst[d], ea[d]);
}

__global__ void ea_norm_kernel(float* __restrict__ ea_mean, const int* __restrict__ deg, int n) {
    int i = blockIdx.x * 256 + threadIdx.x;
    if (i >= n * DIM_ED) return;
    int t = i >> 4;
    float d = fmaxf((float)deg[t], 1.0f);
    ea_mean[i] = ea_mean[i] / d;
}

// single-block exclusive scan of (deg[i]+1) -> off[0..n], off[n]=E+n
__global__ void scan_kernel(const int* __restrict__ deg, int* __restrict__ off, int n) {
    __shared__ int tmp[1024];
    __shared__ int carry_s;
    int tid = threadIdx.x;
    if (tid == 0) carry_s = 0;
    __syncthreads();
    for (int base = 0; base < n; base += 1024) {
        int i = base + tid;
        int v = (i < n) ? (deg[i] + 1) : 0;  // +1 = self loop
        tmp[tid] = v;
        __syncthreads();
        for (int s = 1; s < 1024; s <<= 1) {
            int add = (tid >= s) ? tmp[tid - s] : 0;
            __syncthreads();
            tmp[tid] += add;
            __syncthreads();
        }
        int carry = carry_s;
        if (i < n) off[i] = carry + tmp[tid] - v;  // exclusive
        __syncthreads();
        if (tid == 1023) carry_s = carry + tmp[1023];
        __syncthreads();
    }
    if (tid == 0) off[n] = carry_s;
}

__global__ void scatter_kernel(const int* __restrict__ tgt, const int* __restrict__ off,
                               int* __restrict__ cursor, int* __restrict__ eid, int E_, int n) {
    int e = blockIdx.x * 256 + threadIdx.x;
    if (e >= E_ + n) return;
    int t = (e < E_) ? tgt[e] : (e - E_);
    int pos = atomicAdd(&cursor[t], 1);
    eid[off[t] + pos] = e;
}

// ---------------------------------------------------------------------------
// in_proj: h = relu(x @ W0 + b0)   [40000,64] -> [40000,128]
// 8 nodes / block of 128 threads
// ---------------------------------------------------------------------------
__global__ __launch_bounds__(128) void in_proj_kernel(
    const float* __restrict__ x, const float* __restrict__ W0, const float* __restrict__ b0,
    float* __restrict__ h) {
    int nb = blockIdx.x * 8;
    __shared__ float xs[8][DIM_IN];
    int tid = threadIdx.x;  // 128
    for (int i = tid; i < 8 * DIM_IN; i += 128) xs[i >> 6][i & 63] = x[(size_t)nb * DIM_IN + i];
    __syncthreads();
    float acc[8];
    float bias = b0[tid];
    #pragma unroll
    for (int j = 0; j < 8; j++) acc[j] = bias;
    for (int k = 0; k < DIM_IN; k++) {
        float w = W0[k * DIM_H + tid];
        #pragma unroll
        for (int j = 0; j < 8; j++) acc[j] += xs[j][k] * w;
    }
    #pragma unroll
    for (int j = 0; j < 8; j++) h[(size_t)(nb + j) * DIM_H + tid] = fmaxf(acc[j], 0.0f);
}

// ---------------------------------------------------------------------------
// node projections: xl = h@Wl+bl, xr = h@Wr+br   [40000,128] -> [40000,256] x2
// 8 nodes / block of 256 threads
// ---------------------------------------------------------------------------
__global__ __launch_bounds__(256) void node_proj_kernel(
    const float* __restrict__ h, const float* __restrict__ Wl, const float* __restrict__ bl,
    const float* __restrict__ Wr, const float* __restrict__ br,
    float* __restrict__ xl, float* __restrict__ xr) {
    int nb = blockIdx.x * 8;
    __shared__ float hs[8][DIM_H];
    int tid = threadIdx.x;  // 256
    for (int i = tid; i < 8 * DIM_H; i += 256) hs[i >> 7][i & 127] = h[(size_t)nb * DIM_H + i];
    __syncthreads();
    float accL[8], accR[8];
    float bL = bl[tid], bR = br[tid];
    #pragma unroll
    for (int j = 0; j < 8; j++) { accL[j] = bL; accR[j] = bR; }
    for (int k = 0; k < DIM_H; k++) {
        float wl = Wl[k * 256 + tid];
        float wr = Wr[k * 256 + tid];
        #pragma unroll
        for (int j = 0; j < 8; j++) {
            accL[j] += hs[j][k] * wl;
            accR[j] += hs[j][k] * wr;
        }
    }
    #pragma unroll
    for (int j = 0; j < 8; j++) {
        xl[(size_t)(nb + j) * 256 + tid] = accL[j];
        xr[(size_t)(nb + j) * 256 + tid] = accR[j];
    }
}

// ---------------------------------------------------------------------------
// Fused GATv2 attention + aggregation. One wave per target node.
// Lane owns 4 channels of the 256 (= 2 heads x 128). Lanes 0-31: head 0.
// Online softmax over incoming edges; ef computed on the fly from
// register-resident We column block. No atomics, no E-sized intermediates.
// ---------------------------------------------------------------------------
__global__ __launch_bounds__(256) void gat_attn_kernel(
    const float* __restrict__ xl, const float* __restrict__ xr,
    const float* __restrict__ edge_attr, const float* __restrict__ ea_mean,
    const int* __restrict__ src, const int* __restrict__ csr_eid, const int* __restrict__ csr_off,
    const float* __restrict__ We, const float* __restrict__ att, const float* __restrict__ bconv,
    float* __restrict__ h_new, int n, int E_) {
    int tid = threadIdx.x;
    int wave = tid >> 6, lane = tid & 63;
    int t = blockIdx.x * 4 + wave;
    if (t >= n) return;
    int c0 = lane * 4;

    // Hoist We[:, c0..c0+3] (16x4) and att[c0..c0+3] into registers
    float4 Wcol[DIM_ED];
    #pragma unroll
    for (int k = 0; k < DIM_ED; k++) Wcol[k] = *(const float4*)(We + k * 256 + c0);
    float4 attv = *(const float4*)(att + c0);
    float4 xrt = *(const float4*)(xr + (size_t)t * 256 + c0);

    float4 acc = {0.f, 0.f, 0.f, 0.f};
    float denom = 0.f;
    float mrun = -__builtin_inff();

    int beg = csr_off[t], end = csr_off[t + 1];
    for (int ii = beg; ii < end; ii++) {
        int eid = csr_eid[ii];
        const float* ea;
        int s;
        if (eid < E_) { s = src[eid]; ea = edge_attr + (size_t)eid * DIM_ED; }
        else          { s = t;        ea = ea_mean  + (size_t)t   * DIM_ED; }
        float4 xj = *(const float4*)(xl + (size_t)s * 256 + c0);
        float4 ea0 = *(const float4*)(ea);
        float4 ea1 = *(const float4*)(ea + 4);
        float4 ea2 = *(const float4*)(ea + 8);
        float4 ea3 = *(const float4*)(ea + 12);
        float eav[16] = {ea0.x, ea0.y, ea0.z, ea0.w, ea1.x, ea1.y, ea1.z, ea1.w,
                         ea2.x, ea2.y, ea2.z, ea2.w, ea3.x, ea3.y, ea3.z, ea3.w};
        float4 ef = {0.f, 0.f, 0.f, 0.f};
        #pragma unroll
        for (int k = 0; k < DIM_ED; k++) {
            ef.x += eav[k] * Wcol[k].x;
            ef.y += eav[k] * Wcol[k].y;
            ef.z += eav[k] * Wcol[k].z;
            ef.w += eav[k] * Wcol[k].w;
        }
        float m0 = xj.x + xrt.x + ef.x; m0 = (m0 > 0.f) ? m0 : NEG_SLOPE * m0;
        float m1 = xj.y + xrt.y + ef.y; m1 = (m1 > 0.f) ? m1 : NEG_SLOPE * m1;
        float m2 = xj.z + xrt.z + ef.z; m2 = (m2 > 0.f) ? m2 : NEG_SLOPE * m2;
        float m3 = xj.w + xrt.w + ef.w; m3 = (m3 > 0.f) ? m3 : NEG_SLOPE * m3;
        float logit = attv.x * m0 + attv.y * m1 + attv.z * m2 + attv.w * m3;
        // reduce over the 32 lanes of this head (xor masks 1..16 stay in-group)
        #pragma unroll
        for (int d = 1; d < 32; d <<= 1) logit += __shfl_xor(logit, d, 64);
        // online softmax update
        float mnew = fmaxf(mrun, logit);
        float scale = __expf(mrun - mnew);  // exp(-inf)=0 on first edge
        float p = __expf(logit - mnew);
        denom = denom * scale + p;
        acc.x = acc.x * scale + p * xj.x;
        acc.y = acc.y * scale + p * xj.y;
        acc.z = acc.z * scale + p * xj.z;
        acc.w = acc.w * scale + p * xj.w;
        mrun = mnew;
    }
    float inv = 1.0f / denom;
    float o0 = acc.x * inv, o1 = acc.y * inv, o2 = acc.z * inv, o3 = acc.w * inv;
    // head mean: lane l (head0) pairs with lane l^32 (head1), same channel
    float u0 = 0.5f * (o0 + __shfl_xor(o0, 32, 64));
    float u1 = 0.5f * (o1 + __shfl_xor(o1, 32, 64));
    float u2 = 0.5f * (o2 + __shfl_xor(o2, 32, 64));
    float u3 = 0.5f * (o3 + __shfl_xor(o3, 32, 64));
    if (lane < 32) {
        int hc = c0;  // 0..124
        float4 bc = *(const float4*)(bconv + hc);
        float4 ov;
        ov.x = fmaxf(u0 + bc.x, 0.f);
        ov.y = fmaxf(u1 + bc.y, 0.f);
        ov.z = fmaxf(u2 + bc.z, 0.f);
        ov.w = fmaxf(u3 + bc.w, 0.f);
        *(float4*)(h_new + (size_t)t * DIM_H + hc) = ov;
    }
}

// ---------------------------------------------------------------------------
// decoder: out = sigmoid(relu(h@W1+b1)@W2+b2)   4 nodes / block of 128
// ---------------------------------------------------------------------------
__global__ __launch_bounds__(128) void decoder_kernel(
    const float* __restrict__ h, const float* __restrict__ W1, const float* __restrict__ b1,
    const float* __restrict__ W2, const float* __restrict__ b2, float* __restrict__ out) {
    int nb = blockIdx.x * 4;
    __shared__ float hs[4][DIM_H];
    __shared__ float hid[4][DIM_H];
    int tid = threadIdx.x;  // 128
    for (int i = tid; i < 4 * DIM_H; i += 128) hs[i >> 7][i & 127] = h[(size_t)nb * DIM_H + i];
    __syncthreads();
    float acc[4];
    float bias = b1[tid];
    #pragma unroll
    for (int j = 0; j < 4; j++) acc[j] = bias;
    for (int k = 0; k < DIM_H; k++) {
        float w = W1[k * DIM_H + tid];
        #pragma unroll
        for (int j = 0; j < 4; j++) acc[j] += hs[j][k] * w;
    }
    #pragma unroll
    for (int j = 0; j < 4; j++) hid[j][tid] = fmaxf(acc[j], 0.0f);
    __syncthreads();
    int node = tid >> 5, oc = tid & 31;
    float a = b2[oc];
    for (int k = 0; k < DIM_H; k++) a += hid[node][k] * W2[k * DIM_OUT + oc];
    out[(size_t)(nb + node) * DIM_OUT + oc] = 1.0f / (1.0f + __expf(-a));
}

// ---------------------------------------------------------------------------
extern "C" void kernel_launch(void* const* d_in, const int* in_sizes, int n_in,
                              void* d_out, int out_size, void* d_ws, size_t ws_size,
                              hipStream_t stream) {
    const float* x         = (const float*)d_in[0];
    const int*   edge_index= (const int*)  d_in[1];
    const float* edge_attr = (const float*)d_in[2];
    const float* W0        = (const float*)d_in[3];
    const float* b0        = (const float*)d_in[4];
    const float* Wl        = (const float*)d_in[5];
    const float* bl        = (const float*)d_in[6];
    const float* Wr        = (const float*)d_in[7];
    const float* br        = (const float*)d_in[8];
    const float* We        = (const float*)d_in[9];
    const float* att       = (const float*)d_in[10];
    const float* bconv     = (const float*)d_in[11];
    const float* W1        = (const float*)d_in[12];
    const float* b1        = (const float*)d_in[13];
    const float* W2        = (const float*)d_in[14];
    const float* b2        = (const float*)d_in[15];
    float* out = (float*)d_out;

    const int N_ = N_NODES, E_ = N_EDGES;
    const int* src = edge_index;       // edge_index[0]
    const int* tgt = edge_index + E_;  // edge_index[1]

    char* ws = (char*)d_ws;
    size_t o = 0;
    auto alloc = [&](size_t bytes) -> void* {
        void* p = ws + o;
        o += (bytes + 255) & ~(size_t)255;
        return p;
    };
    float* h0      = (float*)alloc((size_t)N_ * DIM_H * 4);
    float* h1      = (float*)alloc((size_t)N_ * DIM_H * 4);
    float* xl      = (float*)alloc((size_t)N_ * 256 * 4);
    float* xr      = (float*)alloc((size_t)N_ * 256 * 4);
    float* ea_mean = (float*)alloc((size_t)N_ * DIM_ED * 4);
    int*   deg     = (int*)alloc((size_t)N_ * 4);
    int*   off     = (int*)alloc((size_t)(N_ + 1) * 4);
    int*   cursor  = (int*)alloc((size_t)N_ * 4);
    int*   eid     = (int*)alloc((size_t)(E_ + N_) * 4);

    hipMemsetAsync(deg, 0, (size_t)N_ * 4, stream);
    hipMemsetAsync(cursor, 0, (size_t)N_ * 4, stream);
    hipMemsetAsync(ea_mean, 0, (size_t)N_ * DIM_ED * 4, stream);

    deg_ea_kernel<<<(E_ + 255) / 256, 256, 0, stream>>>(tgt, edge_attr, deg, ea_mean, E_);
    ea_norm_kernel<<<(N_ * DIM_ED + 255) / 256, 256, 0, stream>>>(ea_mean, deg, N_);
    scan_kernel<<<1, 1024, 0, stream>>>(deg, off, N_);
    scatter_kernel<<<(E_ + N_ + 255) / 256, 256, 0, stream>>>(tgt, off, cursor, eid, E_, N_);

    in_proj_kernel<<<N_ / 8, 128, 0, stream>>>(x, W0, b0, h0);

    float* hc = h0;
    float* hn = h1;
    for (int l = 0; l < 3; l++) {
        node_proj_kernel<<<N_ / 8, 256, 0, stream>>>(
            hc, Wl + (size_t)l * DIM_H * 256, bl + (size_t)l * 256,
            Wr + (size_t)l * DIM_H * 256, br + (size_t)l * 256, xl, xr);
        gat_attn_kernel<<<N_ / 4, 256, 0, stream>>>(
            xl, xr, edge_attr, ea_mean, src, eid, off,
            We + (size_t)l * DIM_ED * 256, att + (size_t)l * 256, bconv + (size_t)l * DIM_H,
            hn, N_, E_);
        float* tswap = hc; hc = hn; hn = tswap;
    }
    decoder_kernel<<<N_ / 4, 128, 0, stream>>>(hc, W1, b1, W2, b2, out);
}

// Round 3
// 1535.391 us; speedup vs baseline: 1.3688x; 1.3688x over previous
//
#include <hip/hip_runtime.h>
#include <hip/hip_bf16.h>

#define N_NODES 40000
#define N_EDGES 640000
#define DIM_IN 64
#define DIM_H 128
#define DIM_OUT 32
#define DIM_ED 16
#define HEADS 2
#define NEG_SLOPE 0.2f

// ---------------------------------------------------------------------------
// degree count (1 int atomic per edge; no float atomics anywhere)
// ---------------------------------------------------------------------------
__global__ void deg_kernel(const int* __restrict__ tgt, int* __restrict__ deg, int E_) {
    int e = blockIdx.x * 256 + threadIdx.x;
    if (e >= E_) return;
    atomicAdd(&deg[tgt[e]], 1);
}

// ---------------------------------------------------------------------------
// exclusive scan of (deg[i]+1) -> off[0..n]; wave-shuffle scan, 3 barriers/chunk
// ---------------------------------------------------------------------------
__global__ __launch_bounds__(1024) void scan_kernel(const int* __restrict__ deg,
                                                    int* __restrict__ off, int n) {
    __shared__ int wsum[16];
    __shared__ int carry_s;
    int tid = threadIdx.x;
    int wv = tid >> 6, ln = tid & 63;
    if (tid == 0) carry_s = 0;
    __syncthreads();
    for (int base = 0; base < n; base += 1024) {
        int i = base + tid;
        int v = (i < n) ? (deg[i] + 1) : 0;  // +1 = self loop
        int s = v;
        #pragma unroll
        for (int d = 1; d < 64; d <<= 1) {
            int u = __shfl_up(s, d, 64);
            if (ln >= d) s += u;
        }
        if (ln == 63) wsum[wv] = s;
        __syncthreads();
        int woff = 0;
        #pragma unroll
        for (int w = 0; w < 16; w++) woff += (w < wv) ? wsum[w] : 0;
        int carry = carry_s;
        if (i < n) off[i] = carry + woff + s - v;  // exclusive
        __syncthreads();
        if (tid == 1023) carry_s = carry + woff + s;  // full chunk sum
        __syncthreads();
    }
    if (tid == 0) off[n] = carry_s;
}

__global__ void scatter_kernel(const int* __restrict__ tgt, const int* __restrict__ off,
                               int* __restrict__ cursor, int* __restrict__ eid, int E_, int n) {
    int e = blockIdx.x * 256 + threadIdx.x;
    if (e >= E_ + n) return;
    int t = (e < E_) ? tgt[e] : (e - E_);
    int pos = atomicAdd(&cursor[t], 1);
    eid[off[t] + pos] = e;
}

// ---------------------------------------------------------------------------
// ea_mean from CSR: 16 lanes per node, one channel each; no atomics
// ---------------------------------------------------------------------------
__global__ __launch_bounds__(256) void ea_mean_kernel(
    const float* __restrict__ edge_attr, const int* __restrict__ csr_eid,
    const int* __restrict__ csr_off, float* __restrict__ ea_mean, int n, int E_) {
    int tid = blockIdx.x * 256 + threadIdx.x;
    int node = tid >> 4;
    int c = tid & 15;
    if (node >= n) return;
    int beg = csr_off[node], end = csr_off[node + 1];
    float s = 0.f;
    int cnt = 0;
    for (int ii = beg; ii < end; ii++) {
        int eid = csr_eid[ii];
        if (eid < E_) { s += edge_attr[(size_t)eid * DIM_ED + c]; cnt++; }
    }
    ea_mean[(size_t)node * DIM_ED + c] = s / fmaxf((float)cnt, 1.0f);
}

// ---------------------------------------------------------------------------
// in_proj: h = relu(x @ W0 + b0)   [40000,64] -> [40000,128]
// ---------------------------------------------------------------------------
__global__ __launch_bounds__(128) void in_proj_kernel(
    const float* __restrict__ x, const float* __restrict__ W0, const float* __restrict__ b0,
    float* __restrict__ h) {
    int nb = blockIdx.x * 8;
    __shared__ float xs[8][DIM_IN];
    int tid = threadIdx.x;  // 128
    for (int i = tid; i < 8 * DIM_IN; i += 128) xs[i >> 6][i & 63] = x[(size_t)nb * DIM_IN + i];
    __syncthreads();
    float acc[8];
    float bias = b0[tid];
    #pragma unroll
    for (int j = 0; j < 8; j++) acc[j] = bias;
    for (int k = 0; k < DIM_IN; k++) {
        float w = W0[k * DIM_H + tid];
        #pragma unroll
        for (int j = 0; j < 8; j++) acc[j] += xs[j][k] * w;
    }
    #pragma unroll
    for (int j = 0; j < 8; j++) h[(size_t)(nb + j) * DIM_H + tid] = fmaxf(acc[j], 0.0f);
}

// ---------------------------------------------------------------------------
// node projections: xl = h@Wl+bl, xr = h@Wr+br   [40000,128] -> [40000,256] x2
// ---------------------------------------------------------------------------
__global__ __launch_bounds__(256) void node_proj_kernel(
    const float* __restrict__ h, const float* __restrict__ Wl, const float* __restrict__ bl,
    const float* __restrict__ Wr, const float* __restrict__ br,
    float* __restrict__ xl, float* __restrict__ xr) {
    int nb = blockIdx.x * 8;
    __shared__ float hs[8][DIM_H];
    int tid = threadIdx.x;  // 256
    for (int i = tid; i < 8 * DIM_H; i += 256) hs[i >> 7][i & 127] = h[(size_t)nb * DIM_H + i];
    __syncthreads();
    float accL[8], accR[8];
    float bL = bl[tid], bR = br[tid];
    #pragma unroll
    for (int j = 0; j < 8; j++) { accL[j] = bL; accR[j] = bR; }
    for (int k = 0; k < DIM_H; k++) {
        float wl = Wl[k * 256 + tid];
        float wr = Wr[k * 256 + tid];
        #pragma unroll
        for (int j = 0; j < 8; j++) {
            accL[j] += hs[j][k] * wl;
            accR[j] += hs[j][k] * wr;
        }
    }
    #pragma unroll
    for (int j = 0; j < 8; j++) {
        xl[(size_t)(nb + j) * 256 + tid] = accL[j];
        xr[(size_t)(nb + j) * 256 + tid] = accR[j];
    }
}

// ---------------------------------------------------------------------------
// Fused GATv2 attention + aggregation. One wave per target node.
// ---------------------------------------------------------------------------
__global__ __launch_bounds__(256) void gat_attn_kernel(
    const float* __restrict__ xl, const float* __restrict__ xr,
    const float* __restrict__ edge_attr, const float* __restrict__ ea_mean,
    const int* __restrict__ src, const int* __restrict__ csr_eid, const int* __restrict__ csr_off,
    const float* __restrict__ We, const float* __restrict__ att, const float* __restrict__ bconv,
    float* __restrict__ h_new, int n, int E_) {
    int tid = threadIdx.x;
    int wave = tid >> 6, lane = tid & 63;
    int t = blockIdx.x * 4 + wave;
    if (t >= n) return;
    int c0 = lane * 4;

    float4 Wcol[DIM_ED];
    #pragma unroll
    for (int k = 0; k < DIM_ED; k++) Wcol[k] = *(const float4*)(We + k * 256 + c0);
    float4 attv = *(const float4*)(att + c0);
    float4 xrt = *(const float4*)(xr + (size_t)t * 256 + c0);

    float4 acc = {0.f, 0.f, 0.f, 0.f};
    float denom = 0.f;
    float mrun = -__builtin_inff();

    int beg = csr_off[t], end = csr_off[t + 1];
    for (int ii = beg; ii < end; ii++) {
        int eid = csr_eid[ii];
        const float* ea;
        int s;
        if (eid < E_) { s = src[eid]; ea = edge_attr + (size_t)eid * DIM_ED; }
        else          { s = t;        ea = ea_mean  + (size_t)t   * DIM_ED; }
        float4 xj = *(const float4*)(xl + (size_t)s * 256 + c0);
        float4 ea0 = *(const float4*)(ea);
        float4 ea1 = *(const float4*)(ea + 4);
        float4 ea2 = *(const float4*)(ea + 8);
        float4 ea3 = *(const float4*)(ea + 12);
        float eav[16] = {ea0.x, ea0.y, ea0.z, ea0.w, ea1.x, ea1.y, ea1.z, ea1.w,
                         ea2.x, ea2.y, ea2.z, ea2.w, ea3.x, ea3.y, ea3.z, ea3.w};
        float4 ef = {0.f, 0.f, 0.f, 0.f};
        #pragma unroll
        for (int k = 0; k < DIM_ED; k++) {
            ef.x += eav[k] * Wcol[k].x;
            ef.y += eav[k] * Wcol[k].y;
            ef.z += eav[k] * Wcol[k].z;
            ef.w += eav[k] * Wcol[k].w;
        }
        float m0 = xj.x + xrt.x + ef.x; m0 = (m0 > 0.f) ? m0 : NEG_SLOPE * m0;
        float m1 = xj.y + xrt.y + ef.y; m1 = (m1 > 0.f) ? m1 : NEG_SLOPE * m1;
        float m2 = xj.z + xrt.z + ef.z; m2 = (m2 > 0.f) ? m2 : NEG_SLOPE * m2;
        float m3 = xj.w + xrt.w + ef.w; m3 = (m3 > 0.f) ? m3 : NEG_SLOPE * m3;
        float logit = attv.x * m0 + attv.y * m1 + attv.z * m2 + attv.w * m3;
        #pragma unroll
        for (int d = 1; d < 32; d <<= 1) logit += __shfl_xor(logit, d, 64);
        float mnew = fmaxf(mrun, logit);
        float scale = __expf(mrun - mnew);
        float p = __expf(logit - mnew);
        denom = denom * scale + p;
        acc.x = acc.x * scale + p * xj.x;
        acc.y = acc.y * scale + p * xj.y;
        acc.z = acc.z * scale + p * xj.z;
        acc.w = acc.w * scale + p * xj.w;
        mrun = mnew;
    }
    float inv = 1.0f / denom;
    float o0 = acc.x * inv, o1 = acc.y * inv, o2 = acc.z * inv, o3 = acc.w * inv;
    float u0 = 0.5f * (o0 + __shfl_xor(o0, 32, 64));
    float u1 = 0.5f * (o1 + __shfl_xor(o1, 32, 64));
    float u2 = 0.5f * (o2 + __shfl_xor(o2, 32, 64));
    float u3 = 0.5f * (o3 + __shfl_xor(o3, 32, 64));
    if (lane < 32) {
        int hc = c0;
        float4 bc = *(const float4*)(bconv + hc);
        float4 ov;
        ov.x = fmaxf(u0 + bc.x, 0.f);
        ov.y = fmaxf(u1 + bc.y, 0.f);
        ov.z = fmaxf(u2 + bc.z, 0.f);
        ov.w = fmaxf(u3 + bc.w, 0.f);
        *(float4*)(h_new + (size_t)t * DIM_H + hc) = ov;
    }
}

// ---------------------------------------------------------------------------
// decoder: out = sigmoid(relu(h@W1+b1)@W2+b2)
// ---------------------------------------------------------------------------
__global__ __launch_bounds__(128) void decoder_kernel(
    const float* __restrict__ h, const float* __restrict__ W1, const float* __restrict__ b1,
    const float* __restrict__ W2, const float* __restrict__ b2, float* __restrict__ out) {
    int nb = blockIdx.x * 4;
    __shared__ float hs[4][DIM_H];
    __shared__ float hid[4][DIM_H];
    int tid = threadIdx.x;  // 128
    for (int i = tid; i < 4 * DIM_H; i += 128) hs[i >> 7][i & 127] = h[(size_t)nb * DIM_H + i];
    __syncthreads();
    float acc[4];
    float bias = b1[tid];
    #pragma unroll
    for (int j = 0; j < 4; j++) acc[j] = bias;
    for (int k = 0; k < DIM_H; k++) {
        float w = W1[k * DIM_H + tid];
        #pragma unroll
        for (int j = 0; j < 4; j++) acc[j] += hs[j][k] * w;
    }
    #pragma unroll
    for (int j = 0; j < 4; j++) hid[j][tid] = fmaxf(acc[j], 0.0f);
    __syncthreads();
    int node = tid >> 5, oc = tid & 31;
    float a = b2[oc];
    for (int k = 0; k < DIM_H; k++) a += hid[node][k] * W2[k * DIM_OUT + oc];
    out[(size_t)(nb + node) * DIM_OUT + oc] = 1.0f / (1.0f + __expf(-a));
}

// ---------------------------------------------------------------------------
extern "C" void kernel_launch(void* const* d_in, const int* in_sizes, int n_in,
                              void* d_out, int out_size, void* d_ws, size_t ws_size,
                              hipStream_t stream) {
    const float* x         = (const float*)d_in[0];
    const int*   edge_index= (const int*)  d_in[1];
    const float* edge_attr = (const float*)d_in[2];
    const float* W0        = (const float*)d_in[3];
    const float* b0        = (const float*)d_in[4];
    const float* Wl        = (const float*)d_in[5];
    const float* bl        = (const float*)d_in[6];
    const float* Wr        = (const float*)d_in[7];
    const float* br        = (const float*)d_in[8];
    const float* We        = (const float*)d_in[9];
    const float* att       = (const float*)d_in[10];
    const float* bconv     = (const float*)d_in[11];
    const float* W1        = (const float*)d_in[12];
    const float* b1        = (const float*)d_in[13];
    const float* W2        = (const float*)d_in[14];
    const float* b2        = (const float*)d_in[15];
    float* out = (float*)d_out;

    const int N_ = N_NODES, E_ = N_EDGES;
    const int* src = edge_index;       // edge_index[0]
    const int* tgt = edge_index + E_;  // edge_index[1]

    char* ws = (char*)d_ws;
    size_t o = 0;
    auto alloc = [&](size_t bytes) -> void* {
        void* p = ws + o;
        o += (bytes + 255) & ~(size_t)255;
        return p;
    };
    float* h0      = (float*)alloc((size_t)N_ * DIM_H * 4);
    float* h1      = (float*)alloc((size_t)N_ * DIM_H * 4);
    float* xl      = (float*)alloc((size_t)N_ * 256 * 4);
    float* xr      = (float*)alloc((size_t)N_ * 256 * 4);
    float* ea_mean = (float*)alloc((size_t)N_ * DIM_ED * 4);
    int*   deg     = (int*)alloc((size_t)N_ * 4);
    int*   off     = (int*)alloc((size_t)(N_ + 1) * 4);
    int*   cursor  = (int*)alloc((size_t)N_ * 4);
    int*   eid     = (int*)alloc((size_t)(E_ + N_) * 4);

    hipMemsetAsync(deg, 0, (size_t)N_ * 4, stream);
    hipMemsetAsync(cursor, 0, (size_t)N_ * 4, stream);

    deg_kernel<<<(E_ + 255) / 256, 256, 0, stream>>>(tgt, deg, E_);
    scan_kernel<<<1, 1024, 0, stream>>>(deg, off, N_);
    scatter_kernel<<<(E_ + N_ + 255) / 256, 256, 0, stream>>>(tgt, off, cursor, eid, E_, N_);
    ea_mean_kernel<<<(N_ * DIM_ED + 255) / 256, 256, 0, stream>>>(edge_attr, eid, off, ea_mean, N_, E_);

    in_proj_kernel<<<N_ / 8, 128, 0, stream>>>(x, W0, b0, h0);

    float* hc = h0;
    float* hn = h1;
    for (int l = 0; l < 3; l++) {
        node_proj_kernel<<<N_ / 8, 256, 0, stream>>>(
            hc, Wl + (size_t)l * DIM_H * 256, bl + (size_t)l * 256,
            Wr + (size_t)l * DIM_H * 256, br + (size_t)l * 256, xl, xr);
        gat_attn_kernel<<<N_ / 4, 256, 0, stream>>>(
            xl, xr, edge_attr, ea_mean, src, eid, off,
            We + (size_t)l * DIM_ED * 256, att + (size_t)l * 256, bconv + (size_t)l * DIM_H,
            hn, N_, E_);
        float* tswap = hc; hc = hn; hn = tswap;
    }
    decoder_kernel<<<N_ / 4, 128, 0, stream>>>(hc, W1, b1, W2, b2, out);
}